// Round 2
// baseline (605.760 us; speedup 1.0000x reference)
//
#include <hip/hip_runtime.h>
#include <hip/hip_bf16.h>
#include <stdint.h>

// Problem constants (fixed by setup_inputs)
#define T_TOK   16384              // BS*L tokens
#define BSQ     8                  // sequences
#define D1      2048
#define D2      1024

typedef __attribute__((ext_vector_type(8))) short bf16x8;
typedef __attribute__((ext_vector_type(4))) float f32x4;

__device__ __forceinline__ void gll16(const void* g, void* l) {
  __builtin_amdgcn_global_load_lds(
      (const __attribute__((address_space(1))) void*)g,
      (__attribute__((address_space(3))) void*)l, 16, 0, 0);
}

// ---- all 4 weight transpose jobs in ONE launch -----------------------------
__global__ __launch_bounds__(256) void transpose_all(
    const float* __restrict__ W1, const float* __restrict__ W2,
    __hip_bfloat16* __restrict__ bt1, __hip_bfloat16* __restrict__ bt2) {
  __shared__ float tile[32][33];
  int job = blockIdx.x >> 11;          // 2048 blocks per job
  int i = blockIdx.x & 2047;
  const float* in; __hip_bfloat16* out;
  int Cin, ldout, c0, kout0, bx, by;
  if (job < 2) {                       // W1: 2048x2048, halves of 1024 cols
    in = W1; out = bt1; Cin = 2048; ldout = 4096;
    c0 = job ? 1024 : 0; kout0 = job ? 2048 : 0;
    bx = (i & 31) * 32; by = (i >> 5) * 32;     // 32 x 64 tiles
  } else {                             // W2: 1024x4096, halves of 2048 cols
    in = W2; out = bt2; Cin = 4096; ldout = 2048;
    c0 = (job == 3) ? 2048 : 0; kout0 = (job == 3) ? 1024 : 0;
    bx = (i & 63) * 32; by = (i >> 6) * 32;     // 64 x 32 tiles
  }
  int tx = threadIdx.x, ty = threadIdx.y;       // (32, 8)
  #pragma unroll
  for (int q = 0; q < 32; q += 8)
    tile[ty + q][tx] = in[(size_t)(by + ty + q) * Cin + c0 + bx + tx];
  __syncthreads();
  #pragma unroll
  for (int q = 0; q < 32; q += 8)
    out[(size_t)(bx + ty + q) * ldout + kout0 + by + tx] =
        __float2bfloat16(tile[tx][ty + q]);
}

// ---- scatter tokens + both cache-row fills in ONE launch -------------------
__global__ __launch_bounds__(256) void prologue(
    const float* __restrict__ x, const int* __restrict__ loc,
    const float* __restrict__ lf1, const float* __restrict__ lf2,
    const int* __restrict__ pre, const int* __restrict__ lfloc,
    __hip_bfloat16* __restrict__ xt1, __hip_bfloat16* __restrict__ xt2) {
  int b = blockIdx.x;
  if (b < T_TOK) {
    int c = threadIdx.x * 8;
    int r = loc[b];
    const float* src = x + (size_t)b * 2048 + c;
    float4 v0 = *(const float4*)src;
    float4 v1 = *(const float4*)(src + 4);
    union { __hip_bfloat16 h[8]; uint4 u; } o;
    o.h[0] = __float2bfloat16(v0.x); o.h[1] = __float2bfloat16(v0.y);
    o.h[2] = __float2bfloat16(v0.z); o.h[3] = __float2bfloat16(v0.w);
    o.h[4] = __float2bfloat16(v1.x); o.h[5] = __float2bfloat16(v1.y);
    o.h[6] = __float2bfloat16(v1.z); o.h[7] = __float2bfloat16(v1.w);
    *(uint4*)(xt1 + (size_t)r * 2048 + c) = o.u;
  } else if (b < T_TOK + BSQ) {
    int s = b - T_TOK;
    int dst = lfloc[s];
    const float* src = lf1 + (size_t)pre[s] * 2048;
    for (int c = threadIdx.x; c < 2048; c += 256)
      xt1[(size_t)dst * 2048 + c] = __float2bfloat16(src[c]);
  } else {
    int s = b - T_TOK - BSQ;
    int dst = lfloc[s];
    const float* src = lf2 + (size_t)pre[s] * 1024;
    for (int c = threadIdx.x; c < 1024; c += 256)
      xt2[(size_t)dst * 1024 + c] = __float2bfloat16(src[c]);
  }
}

// ---- fused conv GEMM, 256x256 tile, BK=64, 8 waves, 4-phase interleave -----
// m201-style schedule in plain HIP. Per K-tile v (buffer p=v&1), 4 phases:
//   ph1 (m0,k0): 8 ds_read  | stage A-q1q3(v+1) -> buf[p^1]
//   ph2 (m1,k0): 4 ds_read  | stage B-h0 (v+1) -> buf[p^1]
//   ph3 (m0,k1): 8 ds_read  | stage B-h1 (v+1) -> buf[p^1]
//   ph4 (m1,k1): 4 ds_read  | stage A-q0q2(v+2) -> buf[p]  (rows retired @ph3)
// each phase: [reads; stage; (vmcnt @ph4); barrier; lgkm(0); setprio(1);
//              16 MFMA; setprio(0); barrier]
// Single counted vmcnt(2)/tile: in-order VMEM retirement => retiring to the 2
// newest loads confirms all 4 units of tile v+1. Staging only ever overwrites
// regions whose last ds_reads retired >=1 barrier earlier (race-free).
// EPI=1: write bf16(acc + bias) into padded xt2 at row t+s+1  (conv1)
// EPI=2: write f32  (acc + bias + resid[t])  into dense o3    (conv2)
template <int EPI>
__global__ __launch_bounds__(512, 2) void gemm_conv256(
    const __hip_bfloat16* __restrict__ A0,
    const __hip_bfloat16* __restrict__ Bt,
    const float* __restrict__ bias,
    const float* __restrict__ resid,
    __hip_bfloat16* __restrict__ outb,
    float* __restrict__ outf,
    int N, int K, int KH, int ldA, int tnBits) {
  extern __shared__ char smem[];               // 131072 bytes
  const int tid = threadIdx.x;
  const int wave = tid >> 6, lane = tid & 63;
  const int wm = wave & 1, wn = wave >> 1;     // 2 (M) x 4 (N) wave grid

  // XCD-chunked bijective block swizzle (nwg % 8 == 0 for both convs)
  const int nwg = gridDim.x;
  const int bid = blockIdx.x;
  const int lb = (bid & 7) * (nwg >> 3) + (bid >> 3);
  const int tn = lb & ((1 << tnBits) - 1);
  const int tm = lb >> tnBits;

  const int s = tm >> 3;                       // 8 tiles of 256 per sequence
  const size_t r0 = (size_t)tm * 256 + s;      // padded-row base = s*2049 + jb*256
  const int NTH = KH >> 6;                     // K-tiles per segment
  const int NT = NTH * 2;

  const __hip_bfloat16* Bb = Bt + (size_t)tn * 256 * K;

  // ---- staging constants ----
  const int rloc = tid >> 3;                           // wave*8 + lane>>3
  const int c8 = (((tid & 7) ^ (rloc & 7)) << 3);      // swizzled src col (elems)

  // A unit qsel: rows {qsel*64..+63, 128+qsel*64..+63}; 2 loads/thread
  auto stageA = [&](int buf, int t, int qsel) {
    int seg = (t >= NTH) ? 1 : 0;
    int kk = (t - (seg ? NTH : 0)) << 6;
    const __hip_bfloat16* Ar = A0 + (r0 + seg) * (size_t)ldA + kk + c8;
    char* sb = smem + buf * 65536 + (size_t)(qsel * 64 + wave * 8) * 128;
    #pragma unroll
    for (int l = 0; l < 2; ++l) {
      int grow = l * 128 + qsel * 64 + rloc;           // grow&7 == rloc&7
      gll16(Ar + (size_t)grow * ldA, sb + l * 16384);
    }
  };
  // B unit hsel: rows hsel*128 .. +127; 2 loads/thread
  auto stageB = [&](int buf, int t, int hsel) {
    int seg = (t >= NTH) ? 1 : 0;
    int kk = (t - (seg ? NTH : 0)) << 6;
    const __hip_bfloat16* Bs = Bb + (seg ? KH : 0) + kk + c8;
    char* sb = smem + buf * 65536 + 32768 + (size_t)(hsel * 128 + wave * 8) * 128;
    #pragma unroll
    for (int l = 0; l < 2; ++l) {
      int grow = hsel * 128 + l * 64 + rloc;
      gll16(Bs + (size_t)grow * K, sb + l * 8192);
    }
  };

  // ---- fragment-read constants ----
  const int frow = lane & 15;
  const int xr = (lane & 7) << 3;              // element XOR (matches stage swizzle)
  const int fk = (lane >> 4) << 3;             // 0,8,16,24
  const int ek0 = fk ^ xr;
  const int ek1 = (fk | 32) ^ xr;
  int aoff[8], boff[4];
  #pragma unroll
  for (int i = 0; i < 8; ++i) aoff[i] = (wm * 128 + i * 16 + frow) * 64;
  #pragma unroll
  for (int j = 0; j < 4; ++j) boff[j] = (wn * 64 + j * 16 + frow) * 64;

  f32x4 acc[8][4];
  #pragma unroll
  for (int i = 0; i < 8; ++i)
    #pragma unroll
    for (int j = 0; j < 4; ++j)
      #pragma unroll
      for (int e = 0; e < 4; ++e) acc[i][j][e] = 0.0f;

  // ---- prologue: tile 0 complete + steady-state lead unit A-q0q2(1) ----
  stageA(0, 0, 0);
  stageA(0, 0, 1);
  stageB(0, 0, 0);
  stageB(0, 0, 1);
  stageA(1, 1, 0);                              // NT >= 32 always
  asm volatile("s_waitcnt vmcnt(2)" ::: "memory");
  __builtin_amdgcn_s_barrier();
  asm volatile("" ::: "memory");

  // ---- main loop ----
  #pragma unroll 1
  for (int v = 0; v < NT; ++v) {
    const int p = v & 1;
    const __hip_bfloat16* sA_ = (const __hip_bfloat16*)(smem + p * 65536);
    const __hip_bfloat16* sB_ = sA_ + 16384;
    bf16x8 a[4], b[4];

    // ======== phase 1: (m0, k0) ========
    #pragma unroll
    for (int j = 0; j < 4; ++j) b[j] = *(const bf16x8*)(sB_ + boff[j] + ek0);
    #pragma unroll
    for (int i = 0; i < 4; ++i) a[i] = *(const bf16x8*)(sA_ + aoff[i] + ek0);
    if (v + 1 < NT) stageA(p ^ 1, v + 1, 1);
    asm volatile("" ::: "memory");
    __builtin_amdgcn_s_barrier();
    asm volatile("s_waitcnt lgkmcnt(0)" ::: "memory");
    __builtin_amdgcn_sched_barrier(0);
    __builtin_amdgcn_s_setprio(1);
    #pragma unroll
    for (int i = 0; i < 4; ++i)
      #pragma unroll
      for (int j = 0; j < 4; ++j)
        acc[i][j] = __builtin_amdgcn_mfma_f32_16x16x32_bf16(a[i], b[j], acc[i][j], 0, 0, 0);
    __builtin_amdgcn_s_setprio(0);
    asm volatile("" ::: "memory");
    __builtin_amdgcn_s_barrier();
    asm volatile("" ::: "memory");

    // ======== phase 2: (m1, k0) — reuse b ========
    #pragma unroll
    for (int i = 0; i < 4; ++i) a[i] = *(const bf16x8*)(sA_ + aoff[4 + i] + ek0);
    if (v + 1 < NT) stageB(p ^ 1, v + 1, 0);
    asm volatile("" ::: "memory");
    __builtin_amdgcn_s_barrier();
    asm volatile("s_waitcnt lgkmcnt(0)" ::: "memory");
    __builtin_amdgcn_sched_barrier(0);
    __builtin_amdgcn_s_setprio(1);
    #pragma unroll
    for (int i = 0; i < 4; ++i)
      #pragma unroll
      for (int j = 0; j < 4; ++j)
        acc[4 + i][j] = __builtin_amdgcn_mfma_f32_16x16x32_bf16(a[i], b[j], acc[4 + i][j], 0, 0, 0);
    __builtin_amdgcn_s_setprio(0);
    asm volatile("" ::: "memory");
    __builtin_amdgcn_s_barrier();
    asm volatile("" ::: "memory");

    // ======== phase 3: (m0, k1) ========
    #pragma unroll
    for (int j = 0; j < 4; ++j) b[j] = *(const bf16x8*)(sB_ + boff[j] + ek1);
    #pragma unroll
    for (int i = 0; i < 4; ++i) a[i] = *(const bf16x8*)(sA_ + aoff[i] + ek1);
    if (v + 1 < NT) stageB(p ^ 1, v + 1, 1);
    asm volatile("" ::: "memory");
    __builtin_amdgcn_s_barrier();
    asm volatile("s_waitcnt lgkmcnt(0)" ::: "memory");
    __builtin_amdgcn_sched_barrier(0);
    __builtin_amdgcn_s_setprio(1);
    #pragma unroll
    for (int i = 0; i < 4; ++i)
      #pragma unroll
      for (int j = 0; j < 4; ++j)
        acc[i][j] = __builtin_amdgcn_mfma_f32_16x16x32_bf16(a[i], b[j], acc[i][j], 0, 0, 0);
    __builtin_amdgcn_s_setprio(0);
    asm volatile("" ::: "memory");
    __builtin_amdgcn_s_barrier();
    asm volatile("" ::: "memory");

    // ======== phase 4: (m1, k1) — reuse b ========
    #pragma unroll
    for (int i = 0; i < 4; ++i) a[i] = *(const bf16x8*)(sA_ + aoff[4 + i] + ek1);
    if (v + 2 < NT) stageA(p, v + 2, 0);       // A rows q0q2 retired at ph3
    __builtin_amdgcn_sched_barrier(0);
    if (v < NT - 2) { asm volatile("s_waitcnt vmcnt(2)" ::: "memory"); }
    else            { asm volatile("s_waitcnt vmcnt(0)" ::: "memory"); }
    __builtin_amdgcn_s_barrier();
    asm volatile("s_waitcnt lgkmcnt(0)" ::: "memory");
    __builtin_amdgcn_sched_barrier(0);
    __builtin_amdgcn_s_setprio(1);
    #pragma unroll
    for (int i = 0; i < 4; ++i)
      #pragma unroll
      for (int j = 0; j < 4; ++j)
        acc[4 + i][j] = __builtin_amdgcn_mfma_f32_16x16x32_bf16(a[i], b[j], acc[4 + i][j], 0, 0, 0);
    __builtin_amdgcn_s_setprio(0);
    asm volatile("" ::: "memory");
    __builtin_amdgcn_s_barrier();
    asm volatile("" ::: "memory");
  }

  // ---- epilogue ----
  const int t0 = tm * 256 + wm * 128 + ((lane >> 4) << 2);
  const int ccol = tn * 256 + wn * 64 + (lane & 15);
  float bj[4];
  #pragma unroll
  for (int j = 0; j < 4; ++j) bj[j] = bias[ccol + j * 16];

  #pragma unroll
  for (int i = 0; i < 8; ++i)
    #pragma unroll
    for (int p = 0; p < 4; ++p) {
      int tk = t0 + i * 16 + p;
      if (EPI == 1) {
        __hip_bfloat16* dst = outb + ((size_t)tk + s + 1) * N + ccol;
        #pragma unroll
        for (int j = 0; j < 4; ++j)
          dst[j * 16] = __float2bfloat16(acc[i][j][p] + bj[j]);
      } else {
        const float* rsrc = resid + (size_t)tk * N + ccol;
        float* dst = outf + (size_t)tk * N + ccol;
        #pragma unroll
        for (int j = 0; j < 4; ++j)
          dst[j * 16] = acc[i][j][p] + bj[j] + rsrc[j * 16];
      }
    }
}

// ---- RMSNorm over dense o3 [16384, 2048] -----------------------------------
__global__ __launch_bounds__(256) void rmsnorm(
    const float* __restrict__ o3, const float* __restrict__ lnw,
    float* __restrict__ out) {
  __shared__ float red[4];
  int t = blockIdx.x;
  int d = threadIdx.x * 8;
  const float* p = o3 + (size_t)t * 2048 + d;
  float o[8];
  *(float4*)&o[0] = *(const float4*)p;
  *(float4*)&o[4] = *(const float4*)(p + 4);
  float ss = 0.0f;
  #pragma unroll
  for (int k = 0; k < 8; ++k) ss += o[k] * o[k];
  #pragma unroll
  for (int off = 32; off > 0; off >>= 1) ss += __shfl_down(ss, off, 64);
  if ((threadIdx.x & 63) == 0) red[threadIdx.x >> 6] = ss;
  __syncthreads();
  float tot = red[0] + red[1] + red[2] + red[3];
  float sc = rsqrtf(tot * (1.0f / 2048.0f) + 1e-6f);
  float lw[8], res[8];
  *(float4*)&lw[0] = *(const float4*)(lnw + d);
  *(float4*)&lw[4] = *(const float4*)(lnw + d + 4);
  #pragma unroll
  for (int k = 0; k < 8; ++k) res[k] = o[k] * sc * lw[k];
  float* dst = out + (size_t)t * 2048 + d;
  *(float4*)dst = *(float4*)&res[0];
  *(float4*)(dst + 4) = *(float4*)&res[4];
}

extern "C" void kernel_launch(void* const* d_in, const int* in_sizes, int n_in,
                              void* d_out, int out_size, void* d_ws, size_t ws_size,
                              hipStream_t stream) {
  const float* inputs = (const float*)d_in[0];
  const int* pre_idx  = (const int*)d_in[1];
  const int* in_lf_loc = (const int*)d_in[3];
  const int* in_loc  = (const int*)d_in[5];
  const float* lf1 = (const float*)d_in[7];
  const float* lf2 = (const float*)d_in[8];
  const float* W1 = (const float*)d_in[9];
  const float* W2 = (const float*)d_in[10];
  const float* b1 = (const float*)d_in[11];
  const float* b2 = (const float*)d_in[12];
  const float* lnw = (const float*)d_in[13];
  float* out = (float*)d_out;

  // workspace layout
  char* ws = (char*)d_ws;
  float* o3 = (float*)ws;                                     // 16384*2048*4 = 134,217,728
  __hip_bfloat16* xt1 = (__hip_bfloat16*)(ws + 134217728ull); // 16392*2048*2 = 67,141,632
  __hip_bfloat16* xt2 = (__hip_bfloat16*)(ws + 201359360ull); // 16392*1024*2 = 33,570,816
  __hip_bfloat16* bt1 = (__hip_bfloat16*)(ws + 234930176ull); // 1024*4096*2  =  8,388,608
  __hip_bfloat16* bt2 = (__hip_bfloat16*)(ws + 243318784ull); // 2048*2048*2  =  8,388,608

  // allow 128 KiB dynamic LDS (idempotent)
  static int lds_inited = 0;
  if (!lds_inited) {
    lds_inited = 1;
    (void)hipFuncSetAttribute(reinterpret_cast<const void*>(&gemm_conv256<1>),
                              hipFuncAttributeMaxDynamicSharedMemorySize, 131072);
    (void)hipFuncSetAttribute(reinterpret_cast<const void*>(&gemm_conv256<2>),
                              hipFuncAttributeMaxDynamicSharedMemorySize, 131072);
  }

  transpose_all<<<8192, dim3(32, 8), 0, stream>>>(W1, W2, bt1, bt2);
  prologue<<<T_TOK + 2 * BSQ, 256, 0, stream>>>(
      inputs, in_loc, lf1, lf2, pre_idx, in_lf_loc, xt1, xt2);

  // conv1: M=16384, N=1024, K=4096 (KH=2048), A from xt1 (ld 2048); 4x64 blocks
  gemm_conv256<1><<<256, 512, 131072, stream>>>(
      xt1, bt1, b1, nullptr, xt2, nullptr, 1024, 4096, 2048, 2048, 2);

  // conv2: M=16384, N=2048, K=2048 (KH=1024), A from xt2 (ld 1024); 8x64 blocks
  gemm_conv256<2><<<512, 512, 131072, stream>>>(
      xt2, bt2, b2, inputs, nullptr, o3, 2048, 2048, 1024, 1024, 3);

  rmsnorm<<<T_TOK, 256, 0, stream>>>(o3, lnw, out);
}

// Round 3
// 573.780 us; speedup vs baseline: 1.0557x; 1.0557x over previous
//
#include <hip/hip_runtime.h>
#include <hip/hip_bf16.h>
#include <stdint.h>

// Problem constants (fixed by setup_inputs)
#define T_TOK   16384              // BS*L tokens
#define BSQ     8                  // sequences
#define D1      2048
#define D2      1024

typedef __attribute__((ext_vector_type(8))) short bf16x8;
typedef __attribute__((ext_vector_type(4))) float f32x4;

__device__ __forceinline__ void gll16(const void* g, void* l) {
  __builtin_amdgcn_global_load_lds(
      (const __attribute__((address_space(1))) void*)g,
      (__attribute__((address_space(3))) void*)l, 16, 0, 0);
}

// ---- all 4 weight transpose jobs in ONE launch -----------------------------
__global__ __launch_bounds__(256) void transpose_all(
    const float* __restrict__ W1, const float* __restrict__ W2,
    __hip_bfloat16* __restrict__ bt1, __hip_bfloat16* __restrict__ bt2) {
  __shared__ float tile[32][33];
  int job = blockIdx.x >> 11;          // 2048 blocks per job
  int i = blockIdx.x & 2047;
  const float* in; __hip_bfloat16* out;
  int Cin, ldout, c0, kout0, bx, by;
  if (job < 2) {                       // W1: 2048x2048, halves of 1024 cols
    in = W1; out = bt1; Cin = 2048; ldout = 4096;
    c0 = job ? 1024 : 0; kout0 = job ? 2048 : 0;
    bx = (i & 31) * 32; by = (i >> 5) * 32;     // 32 x 64 tiles
  } else {                             // W2: 1024x4096, halves of 2048 cols
    in = W2; out = bt2; Cin = 4096; ldout = 2048;
    c0 = (job == 3) ? 2048 : 0; kout0 = (job == 3) ? 1024 : 0;
    bx = (i & 63) * 32; by = (i >> 6) * 32;     // 64 x 32 tiles
  }
  int tx = threadIdx.x, ty = threadIdx.y;       // (32, 8)
  #pragma unroll
  for (int q = 0; q < 32; q += 8)
    tile[ty + q][tx] = in[(size_t)(by + ty + q) * Cin + c0 + bx + tx];
  __syncthreads();
  #pragma unroll
  for (int q = 0; q < 32; q += 8)
    out[(size_t)(bx + ty + q) * ldout + kout0 + by + tx] =
        __float2bfloat16(tile[tx][ty + q]);
}

// ---- scatter tokens + both cache-row fills in ONE launch -------------------
__global__ __launch_bounds__(256) void prologue(
    const float* __restrict__ x, const int* __restrict__ loc,
    const float* __restrict__ lf1, const float* __restrict__ lf2,
    const int* __restrict__ pre, const int* __restrict__ lfloc,
    __hip_bfloat16* __restrict__ xt1, __hip_bfloat16* __restrict__ xt2) {
  int b = blockIdx.x;
  if (b < T_TOK) {
    int c = threadIdx.x * 8;
    int r = loc[b];
    const float* src = x + (size_t)b * 2048 + c;
    float4 v0 = *(const float4*)src;
    float4 v1 = *(const float4*)(src + 4);
    union { __hip_bfloat16 h[8]; uint4 u; } o;
    o.h[0] = __float2bfloat16(v0.x); o.h[1] = __float2bfloat16(v0.y);
    o.h[2] = __float2bfloat16(v0.z); o.h[3] = __float2bfloat16(v0.w);
    o.h[4] = __float2bfloat16(v1.x); o.h[5] = __float2bfloat16(v1.y);
    o.h[6] = __float2bfloat16(v1.z); o.h[7] = __float2bfloat16(v1.w);
    *(uint4*)(xt1 + (size_t)r * 2048 + c) = o.u;
  } else if (b < T_TOK + BSQ) {
    int s = b - T_TOK;
    int dst = lfloc[s];
    const float* src = lf1 + (size_t)pre[s] * 2048;
    for (int c = threadIdx.x; c < 2048; c += 256)
      xt1[(size_t)dst * 2048 + c] = __float2bfloat16(src[c]);
  } else {
    int s = b - T_TOK - BSQ;
    int dst = lfloc[s];
    const float* src = lf2 + (size_t)pre[s] * 1024;
    for (int c = threadIdx.x; c < 1024; c += 256)
      xt2[(size_t)dst * 1024 + c] = __float2bfloat16(src[c]);
  }
}

// ---- fused conv GEMM, 256x256 tile, BK=64, 8 waves, reg-pipelined ----------
// Register-level software pipeline: each 16-MFMA cluster runs while the NEXT
// cluster's ds_reads are in flight (compiler inserts counted lgkmcnt before
// first use — no explicit waits inside the tile). 2 barriers per K-tile:
//   mid  (lgkm(0)+bar): all buf-p reads CU-drained -> ph3 may stage v+2 into p
//   bndy (vmcnt(8)+bar): tile v+1 (staged 2 tiles ago) landed in p^1
// vmcnt never drains to 0 in steady state.
// EPI=1: write bf16(acc + bias) into padded xt2 at row t+s+1  (conv1)
// EPI=2: write f32  (acc + bias + resid[t])  into dense o3    (conv2)
template <int EPI>
__global__ __launch_bounds__(512, 2) void gemm_conv256(
    const __hip_bfloat16* __restrict__ A0,
    const __hip_bfloat16* __restrict__ Bt,
    const float* __restrict__ bias,
    const float* __restrict__ resid,
    __hip_bfloat16* __restrict__ outb,
    float* __restrict__ outf,
    int N, int K, int KH, int ldA, int tnBits) {
  extern __shared__ char smem[];               // 131072 bytes
  const int tid = threadIdx.x;
  const int wave = tid >> 6, lane = tid & 63;
  const int wm = wave & 1, wn = wave >> 1;     // 2 (M) x 4 (N) wave grid

  // XCD-chunked bijective block swizzle (nwg % 8 == 0 for both convs)
  const int nwg = gridDim.x;
  const int bid = blockIdx.x;
  const int lb = (bid & 7) * (nwg >> 3) + (bid >> 3);
  const int tn = lb & ((1 << tnBits) - 1);
  const int tm = lb >> tnBits;

  const int s = tm >> 3;                       // 8 tiles of 256 per sequence
  const size_t r0 = (size_t)tm * 256 + s;      // padded-row base = s*2049 + jb*256
  const int NTH = KH >> 6;                     // K-tiles per segment
  const int NT = NTH * 2;

  const __hip_bfloat16* Bb = Bt + (size_t)tn * 256 * K;

  // ---- staging constants ----
  const int rloc = tid >> 3;                           // wave*8 + lane>>3
  const int c8 = (((tid & 7) ^ (rloc & 7)) << 3);      // swizzled src col (elems)

  // A unit qsel: rows {qsel*64..+63, 128+qsel*64..+63}; 2 loads/thread
  auto stageA = [&](int buf, int t, int qsel) {
    int seg = (t >= NTH) ? 1 : 0;
    int kk = (t - (seg ? NTH : 0)) << 6;
    const __hip_bfloat16* Ar = A0 + (r0 + seg) * (size_t)ldA + kk + c8;
    char* sb = smem + buf * 65536 + (size_t)(qsel * 64 + wave * 8) * 128;
    #pragma unroll
    for (int l = 0; l < 2; ++l) {
      int grow = l * 128 + qsel * 64 + rloc;           // grow&7 == rloc&7
      gll16(Ar + (size_t)grow * ldA, sb + l * 16384);
    }
  };
  // B unit hsel: rows hsel*128 .. +127; 2 loads/thread
  auto stageB = [&](int buf, int t, int hsel) {
    int seg = (t >= NTH) ? 1 : 0;
    int kk = (t - (seg ? NTH : 0)) << 6;
    const __hip_bfloat16* Bs = Bb + (seg ? KH : 0) + kk + c8;
    char* sb = smem + buf * 65536 + 32768 + (size_t)(hsel * 128 + wave * 8) * 128;
    #pragma unroll
    for (int l = 0; l < 2; ++l) {
      int grow = hsel * 128 + l * 64 + rloc;
      gll16(Bs + (size_t)grow * K, sb + l * 8192);
    }
  };

  // ---- fragment-read constants ----
  const int frow = lane & 15;
  const int xr = (lane & 7) << 3;              // element XOR (matches stage swizzle)
  const int fk = (lane >> 4) << 3;             // 0,8,16,24
  const int ek0 = fk ^ xr;
  const int ek1 = (fk | 32) ^ xr;
  int aoff[8], boff[4];
  #pragma unroll
  for (int i = 0; i < 8; ++i) aoff[i] = (wm * 128 + i * 16 + frow) * 64;
  #pragma unroll
  for (int j = 0; j < 4; ++j) boff[j] = (wn * 64 + j * 16 + frow) * 64;

  f32x4 acc[8][4];
  #pragma unroll
  for (int i = 0; i < 8; ++i)
    #pragma unroll
    for (int j = 0; j < 4; ++j)
      #pragma unroll
      for (int e = 0; e < 4; ++e) acc[i][j][e] = 0.0f;

  bf16x8 a0[4], a1[4], a2[4], a3[4], b0[4], b1[4];

  auto rdA = [&](bf16x8* d, const __hip_bfloat16* base, int mh, int ek) {
    #pragma unroll
    for (int i = 0; i < 4; ++i)
      d[i] = *(const bf16x8*)(base + aoff[mh * 4 + i] + ek);
  };
  auto rdB = [&](bf16x8* d, const __hip_bfloat16* base, int ek) {
    #pragma unroll
    for (int j = 0; j < 4; ++j)
      d[j] = *(const bf16x8*)(base + boff[j] + ek);
  };
  auto mm = [&](int mh, const bf16x8* a, const bf16x8* b) {
    #pragma unroll
    for (int i = 0; i < 4; ++i)
      #pragma unroll
      for (int j = 0; j < 4; ++j)
        acc[mh * 4 + i][j] = __builtin_amdgcn_mfma_f32_16x16x32_bf16(
            a[i], b[j], acc[mh * 4 + i][j], 0, 0, 0);
  };

  // ---- prologue: stage tiles 0 and 1 fully; wait tile 0; load first frags --
  stageA(0, 0, 0); stageA(0, 0, 1); stageB(0, 0, 0); stageB(0, 0, 1);
  stageA(1, 1, 0); stageA(1, 1, 1); stageB(1, 1, 0); stageB(1, 1, 1);
  asm volatile("s_waitcnt vmcnt(8)" ::: "memory");
  __builtin_amdgcn_s_barrier();
  asm volatile("" ::: "memory");

  const __hip_bfloat16* sA_ = (const __hip_bfloat16*)smem;
  const __hip_bfloat16* sB_ = sA_ + 16384;
  rdB(b0, sB_, ek0);
  rdA(a0, sA_, 0, ek0);

  // ---- main loop ----
  #pragma unroll 1
  for (int v = 0; v < NT; ++v) {
    const int p = v & 1;

    // ph0: read a1 (m1,k0)  || mfma (a0,b0)
    rdA(a1, sA_, 1, ek0);
    mm(0, a0, b0);

    // ph1: read b1,a2 (k1)  || mfma (a1,b0)
    rdB(b1, sB_, ek1);
    rdA(a2, sA_, 0, ek1);
    mm(1, a1, b0);

    // ph2: read a3 (m1,k1)  || mfma (a2,b1)
    rdA(a3, sA_, 1, ek1);
    mm(0, a2, b1);

    // mid sync: all of this wave's buf-p reads drained; CU-wide via barrier
    asm volatile("s_waitcnt lgkmcnt(0)" ::: "memory");
    __builtin_amdgcn_s_barrier();
    asm volatile("" ::: "memory");

    // ph3: stage tile v+2 into p (now safe) || mfma (a3,b1)
    if (v + 2 < NT) {
      stageA(p, v + 2, 0); stageA(p, v + 2, 1);
      stageB(p, v + 2, 0); stageB(p, v + 2, 1);
    }
    mm(1, a3, b1);

    // boundary: tile v+1 (staged two tiles ago) landed in p^1
    if (v + 1 < NT) {
      if (v + 2 < NT) { asm volatile("s_waitcnt vmcnt(8)" ::: "memory"); }
      else            { asm volatile("s_waitcnt vmcnt(0)" ::: "memory"); }
      __builtin_amdgcn_s_barrier();
      asm volatile("" ::: "memory");
      sA_ = (const __hip_bfloat16*)(smem + (p ^ 1) * 65536);
      sB_ = sA_ + 16384;
      rdB(b0, sB_, ek0);                 // overlap ph3 MFMAs still in pipe
      rdA(a0, sA_, 0, ek0);
    }
  }

  // ---- epilogue ----
  const int t0 = tm * 256 + wm * 128 + ((lane >> 4) << 2);
  const int ccol = tn * 256 + wn * 64 + (lane & 15);
  float bj[4];
  #pragma unroll
  for (int j = 0; j < 4; ++j) bj[j] = bias[ccol + j * 16];

  #pragma unroll
  for (int i = 0; i < 8; ++i)
    #pragma unroll
    for (int p = 0; p < 4; ++p) {
      int tk = t0 + i * 16 + p;
      if (EPI == 1) {
        __hip_bfloat16* dst = outb + ((size_t)tk + s + 1) * N + ccol;
        #pragma unroll
        for (int j = 0; j < 4; ++j)
          dst[j * 16] = __float2bfloat16(acc[i][j][p] + bj[j]);
      } else {
        const float* rsrc = resid + (size_t)tk * N + ccol;
        float* dst = outf + (size_t)tk * N + ccol;
        #pragma unroll
        for (int j = 0; j < 4; ++j)
          dst[j * 16] = acc[i][j][p] + bj[j] + rsrc[j * 16];
      }
    }
}

// ---- RMSNorm over dense o3 [16384, 2048] -----------------------------------
__global__ __launch_bounds__(256) void rmsnorm(
    const float* __restrict__ o3, const float* __restrict__ lnw,
    float* __restrict__ out) {
  __shared__ float red[4];
  int t = blockIdx.x;
  int d = threadIdx.x * 8;
  const float* p = o3 + (size_t)t * 2048 + d;
  float o[8];
  *(float4*)&o[0] = *(const float4*)p;
  *(float4*)&o[4] = *(const float4*)(p + 4);
  float ss = 0.0f;
  #pragma unroll
  for (int k = 0; k < 8; ++k) ss += o[k] * o[k];
  #pragma unroll
  for (int off = 32; off > 0; off >>= 1) ss += __shfl_down(ss, off, 64);
  if ((threadIdx.x & 63) == 0) red[threadIdx.x >> 6] = ss;
  __syncthreads();
  float tot = red[0] + red[1] + red[2] + red[3];
  float sc = rsqrtf(tot * (1.0f / 2048.0f) + 1e-6f);
  float lw[8], res[8];
  *(float4*)&lw[0] = *(const float4*)(lnw + d);
  *(float4*)&lw[4] = *(const float4*)(lnw + d + 4);
  #pragma unroll
  for (int k = 0; k < 8; ++k) res[k] = o[k] * sc * lw[k];
  float* dst = out + (size_t)t * 2048 + d;
  *(float4*)dst = *(float4*)&res[0];
  *(float4*)(dst + 4) = *(float4*)&res[4];
}

extern "C" void kernel_launch(void* const* d_in, const int* in_sizes, int n_in,
                              void* d_out, int out_size, void* d_ws, size_t ws_size,
                              hipStream_t stream) {
  const float* inputs = (const float*)d_in[0];
  const int* pre_idx  = (const int*)d_in[1];
  const int* in_lf_loc = (const int*)d_in[3];
  const int* in_loc  = (const int*)d_in[5];
  const float* lf1 = (const float*)d_in[7];
  const float* lf2 = (const float*)d_in[8];
  const float* W1 = (const float*)d_in[9];
  const float* W2 = (const float*)d_in[10];
  const float* b1 = (const float*)d_in[11];
  const float* b2 = (const float*)d_in[12];
  const float* lnw = (const float*)d_in[13];
  float* out = (float*)d_out;

  // workspace layout
  char* ws = (char*)d_ws;
  float* o3 = (float*)ws;                                     // 16384*2048*4 = 134,217,728
  __hip_bfloat16* xt1 = (__hip_bfloat16*)(ws + 134217728ull); // 16392*2048*2 = 67,141,632
  __hip_bfloat16* xt2 = (__hip_bfloat16*)(ws + 201359360ull); // 16392*1024*2 = 33,570,816
  __hip_bfloat16* bt1 = (__hip_bfloat16*)(ws + 234930176ull); // 1024*4096*2  =  8,388,608
  __hip_bfloat16* bt2 = (__hip_bfloat16*)(ws + 243318784ull); // 2048*2048*2  =  8,388,608

  // allow 128 KiB dynamic LDS (idempotent)
  static int lds_inited = 0;
  if (!lds_inited) {
    lds_inited = 1;
    (void)hipFuncSetAttribute(reinterpret_cast<const void*>(&gemm_conv256<1>),
                              hipFuncAttributeMaxDynamicSharedMemorySize, 131072);
    (void)hipFuncSetAttribute(reinterpret_cast<const void*>(&gemm_conv256<2>),
                              hipFuncAttributeMaxDynamicSharedMemorySize, 131072);
  }

  transpose_all<<<8192, dim3(32, 8), 0, stream>>>(W1, W2, bt1, bt2);
  prologue<<<T_TOK + 2 * BSQ, 256, 0, stream>>>(
      inputs, in_loc, lf1, lf2, pre_idx, in_lf_loc, xt1, xt2);

  // conv1: M=16384, N=1024, K=4096 (KH=2048), A from xt1 (ld 2048); 4x64 blocks
  gemm_conv256<1><<<256, 512, 131072, stream>>>(
      xt1, bt1, b1, nullptr, xt2, nullptr, 1024, 4096, 2048, 2048, 2);

  // conv2: M=16384, N=2048, K=2048 (KH=1024), A from xt2 (ld 1024); 8x64 blocks
  gemm_conv256<2><<<512, 512, 131072, stream>>>(
      xt2, bt2, b2, inputs, nullptr, o3, 2048, 2048, 1024, 1024, 3);

  rmsnorm<<<T_TOK, 256, 0, stream>>>(o3, lnw, out);
}